// Round 18
// baseline (116.084 us; speedup 1.0000x reference)
//
#include <hip/hip_runtime.h>
#include <hip/hip_bf16.h>
#include <math.h>

typedef __bf16 bf16_t;
typedef __bf16 bf16x8 __attribute__((ext_vector_type(8)));
typedef __bf16 bf16x4 __attribute__((ext_vector_type(4)));
typedef __bf16 bf16x2 __attribute__((ext_vector_type(2)));
typedef float  f32x4  __attribute__((ext_vector_type(4)));
typedef float  f32x16 __attribute__((ext_vector_type(16)));

// ---------------- async global->LDS (16B per lane, wave-uniform LDS base) ----
__device__ __forceinline__ void gload_lds16(const void* g, void* l) {
  __builtin_amdgcn_global_load_lds((const __attribute__((address_space(1))) void*)g,
                                   (__attribute__((address_space(3))) void*)l,
                                   16, 0, 0);
}

__device__ __forceinline__ unsigned pk2(float a, float b) {
  union { bf16x2 h; unsigned u; } x;
  x.h[0] = (bf16_t)a; x.h[1] = (bf16_t)b;
  return x.u;
}
__device__ __forceinline__ bf16x8 frag4(unsigned w0, unsigned w1, unsigned w2, unsigned w3) {
  union { unsigned u[4]; bf16x8 f; } x;
  x.u[0] = w0; x.u[1] = w1; x.u[2] = w2; x.u[3] = w3;
  return x.f;
}
// permlane32_swap: D.lo=a.lo, D.hi=b.lo ; E.lo=a.hi, E.hi=b.hi  (lane l <-> l^32 mix)
__device__ __forceinline__ void pls(unsigned a, unsigned b, unsigned& x, unsigned& y) {
  auto rr = __builtin_amdgcn_permlane32_swap(a, b, false, false);
  x = ((unsigned*)&rr)[0];
  y = ((unsigned*)&rr)[1];
}

// ---------------- fused prep: x->bf16, W transposes, rope cs table -----------
// grid concat (all independent): [0,4096) convert, [4096,7168) Wqkv^T,
// [7168,8192) Wproj^T, [8192,8704) interleaved (cos,sin) table.
__global__ __launch_bounds__(256) void prep_all(const float* __restrict__ x,
                                                const float* __restrict__ Wqkv,
                                                const float* __restrict__ Wproj,
                                                bf16_t* __restrict__ xb,
                                                bf16_t* __restrict__ wqkvt,
                                                bf16_t* __restrict__ wprojt,
                                                float2* __restrict__ csT) {
  __shared__ float tile[32][33];
  int bx = blockIdx.x;
  if (bx < 4096) {
    int idx = (bx * 256 + threadIdx.x) * 4;
    float4 v = *(const float4*)(x + idx);
    bf16x4 o;
    o[0] = (bf16_t)v.x; o[1] = (bf16_t)v.y; o[2] = (bf16_t)v.z; o[3] = (bf16_t)v.w;
    *(bf16x4*)(xb + idx) = o;
  } else if (bx < 8192) {
    const float* W; bf16_t* Wt; int K, N, n0, k0;
    if (bx < 7168) {
      W = Wqkv; Wt = wqkvt; K = 1024; N = 3072;
      int b = bx - 4096; n0 = (b % 96) * 32; k0 = (b / 96) * 32;
    } else {
      W = Wproj; Wt = wprojt; K = 1024; N = 1024;
      int b = bx - 7168; n0 = (b & 31) * 32; k0 = (b >> 5) * 32;
    }
    int tx = threadIdx.x & 31, ty = threadIdx.x >> 5;
    #pragma unroll
    for (int i = 0; i < 4; ++i) {
      int k = ty + i * 8;
      tile[k][tx] = W[(size_t)(k0 + k) * N + n0 + tx];
    }
    __syncthreads();
    #pragma unroll
    for (int i = 0; i < 4; ++i) {
      int r = ty + i * 8;
      Wt[(size_t)(n0 + r) * K + k0 + tx] = (bf16_t)tile[tx][r];
    }
  } else {
    int b = bx - 8192;
    int t = b * 4 + (threadIdx.x >> 6);
    int d = threadIdx.x & 63;
    float inv = __expf(-logf(10000.f) * (float)(d & 31) * (1.f / 32.f));
    float ang = (float)t * inv;
    float2 cs; cs.x = cosf(ang); cs.y = sinf(ang);
    csT[t * 64 + d] = cs;
  }
}

// ---------------- GEMM: C = A(MxK) * Bt(NxK)^T --------------------------------
// 64x128 tile (BM=64): doubles the grid vs 128^2 -> 6 blocks/CU for QKV
// (r17 showed the GEMM is latency/TLP-bound: FETCH halved, time flat, occupancy
// pinned by grid at 3/CU). 4 waves as 2x2; wave owns 32x64 (acc[2][4], 32 VGPR).
// LDS 24 KB (lA 8K + lB 16K), single-buffered (r16: dbuf regressed).
// BK=64, T2 swizzle (rule-21). XCD RECTANGLE swizzle (XW x YH chunk rects).
// MODE 0: plain f32 C (proj). MODE 1: fused QKV epilogue — region-pure blocks
// (bx 0-7 Q, 8-15 K, 16-23 V); RoPE in-register (partner d^32 = acc[m][n^2][r]);
// Q scaled by 0.125*log2(e); V -> compact Vtmp. NOTE r14: fusing V-transpose
// costs VGPR -> +18us. Keep Vtmp + separate prep_vt.
template <int MODE>
__global__ __launch_bounds__(256) void gemm_bt(const bf16_t* __restrict__ A,
                                               const bf16_t* __restrict__ Bt,
                                               void* __restrict__ Cout,
                                               const float2* __restrict__ csT,
                                               bf16_t* __restrict__ Qo,
                                               bf16_t* __restrict__ Ko,
                                               bf16_t* __restrict__ Vt,
                                               int M, int N, int K, int XW) {
  const int tid = threadIdx.x;
  const int l = tid & 63, w = tid >> 6;
  const int lr = l & 15, lg = l >> 4;
  const int nwgx = gridDim.x, nwgy = gridDim.y;
  const int orig = blockIdx.y * nwgx + blockIdx.x;
  // XCD rectangle mapping: xcd gets a XW x YH rect; bijective partition.
  const int xcd = orig & 7;
  const int i = orig >> 3;                 // 0 .. nwg/8-1
  const int nrc = nwgx / XW;               // rect columns
  const int YH = (nwgx * nwgy) / (8 * XW); // rect height
  const int bx = (xcd % nrc) * XW + (i % XW);
  const int by = (xcd / nrc) * YH + (i / XW);
  const int wr = w >> 1, wc = w & 1;
  __shared__ __align__(16) bf16_t lA[64 * 64];
  __shared__ __align__(16) bf16_t lB[128 * 64];
  f32x4 acc[2][4];
  const f32x4 zf = {0.f, 0.f, 0.f, 0.f};
  #pragma unroll
  for (int m = 0; m < 2; ++m)
    #pragma unroll
    for (int n = 0; n < 4; ++n) acc[m][n] = zf;

  const int sr8 = l >> 3;                            // 0..7
  const int sc16 = ((l & 7) * 16) ^ (sr8 << 4);      // swizzled src col-byte
  const char* Ab = (const char*)(A + (size_t)(by * 64) * K);
  const char* Bb = (const char*)(Bt + (size_t)(bx * 128) * K);
  const size_t rowb = (size_t)K * 2;                 // row stride bytes

  for (int k0 = 0; k0 < 2 * K; k0 += 128) {
    #pragma unroll
    for (int p = 0; p < 2; ++p) {
      int row = p * 32 + w * 8 + sr8;
      gload_lds16(Ab + (size_t)row * rowb + k0 + sc16, (char*)lA + p * 4096 + w * 1024);
    }
    #pragma unroll
    for (int p = 0; p < 4; ++p) {
      int row = p * 32 + w * 8 + sr8;
      gload_lds16(Bb + (size_t)row * rowb + k0 + sc16, (char*)lB + p * 4096 + w * 1024);
    }
    __syncthreads();
    #pragma unroll
    for (int kk = 0; kk < 2; ++kk) {
      bf16x8 aF[2], bF[4];
      #pragma unroll
      for (int m = 0; m < 2; ++m) {
        int row = wr * 32 + m * 16 + lr;
        aF[m] = *(const bf16x8*)((const char*)lA + row * 128 +
                                 ((kk * 64 + lg * 16) ^ ((row & 7) << 4)));
      }
      #pragma unroll
      for (int n = 0; n < 4; ++n) {
        int row = wc * 64 + n * 16 + lr;
        bF[n] = *(const bf16x8*)((const char*)lB + row * 128 +
                                 ((kk * 64 + lg * 16) ^ ((row & 7) << 4)));
      }
      #pragma unroll
      for (int m = 0; m < 2; ++m)
        #pragma unroll
        for (int n = 0; n < 4; ++n)
          acc[m][n] = __builtin_amdgcn_mfma_f32_16x16x32_bf16(aF[m], bF[n], acc[m][n], 0, 0, 0);
    }
    __syncthreads();
  }

  const int orow0 = by * 64 + wr * 32;
  if (MODE == 0) {
    const int ocol0 = bx * 128 + wc * 64;
    float* C = (float*)Cout;
    #pragma unroll
    for (int m = 0; m < 2; ++m)
      #pragma unroll
      for (int n = 0; n < 4; ++n)
        #pragma unroll
        for (int r = 0; r < 4; ++r)
          C[(size_t)(orow0 + m * 16 + lg * 4 + r) * N + ocol0 + n * 16 + lr] =
              acc[m][n][r];
  } else {
    const int region = bx >> 3;                 // 0 Q, 1 K, 2 V
    const int h = ((bx & 7) << 1) + wc;         // head within region
    bf16_t* dst = (region == 0) ? Qo : ((region == 1) ? Ko : Vt);
    const float qsc = (region == 0) ? 0.18033688011112042f : 1.0f;
    #pragma unroll
    for (int m = 0; m < 2; ++m)
      #pragma unroll
      for (int r = 0; r < 4; ++r) {
        int grow = orow0 + m * 16 + lg * 4 + r;
        int bb = grow >> 11, t = grow & 2047;
        bf16_t* drow = dst + (((size_t)(bb * 16 + h) * 2048 + t) << 6);
        if (region < 2) {
          #pragma unroll
          for (int n = 0; n < 4; ++n) {
            int d = n * 16 + lr;
            float2 cs = csT[t * 64 + d];
            float v = acc[m][n][r];
            float pv = acc[m][n ^ 2][r];
            float rot = (n < 2) ? -pv : pv;
            drow[d] = (bf16_t)((v * cs.x + rot * cs.y) * qsc);
          }
        } else {
          #pragma unroll
          for (int n = 0; n < 4; ++n)
            drow[n * 16 + lr] = (bf16_t)acc[m][n][r];
        }
      }
  }
}

// ---------------- V transpose: Vtmp (b,h,t,d) -> VT (B,H,Dh,T) ---------------
__global__ __launch_bounds__(256) void prep_vt(const bf16_t* __restrict__ Vtmp,
                                               bf16_t* __restrict__ VT) {
  int bh = blockIdx.x & 31;
  int t0 = (blockIdx.x >> 5) * 64;
  __shared__ __align__(16) bf16_t tile[64][72];
  int r = threadIdx.x >> 2, c4 = threadIdx.x & 3;
  const bf16_t* src = Vtmp + ((size_t)bh * 2048 + t0 + r) * 64 + c4 * 16;
  *(bf16x8*)&tile[r][c4 * 16] = *(const bf16x8*)src;
  *(bf16x8*)&tile[r][c4 * 16 + 8] = *(const bf16x8*)(src + 8);
  __syncthreads();
  bf16x8 v0, v1;
  #pragma unroll
  for (int i = 0; i < 8; ++i) v0[i] = tile[c4 * 16 + i][r];
  #pragma unroll
  for (int i = 0; i < 8; ++i) v1[i] = tile[c4 * 16 + 8 + i][r];
  bf16_t* dst = VT + ((size_t)bh * 64 + r) * 2048 + t0 + c4 * 16;
  *(bf16x8*)dst = v0;
  *(bf16x8*)(dst + 8) = v1;
}

// ---------------- causal flash attention --------------------------------------
// 512 blocks x 512 threads (8 waves = 4 q-waves x 2 kv-halves). Each (bh, qi)
// exactly once; slot-balanced pairing (block c and c+256 share a CU slot).
// Double-buffered K/V per half; LDS 64 KB, 2 blocks/CU. bh = L&31 keeps
// XCD/L2 grouping. No max tracking. Swapped-QK 32x32 MFMA; permlane P-pack.
// NOTE: oacc[2][2] 4-chain variant overflows unified VGPR/AGPR -> spills
// (r10: FETCH 12->58 MB, 2x time). q-half block split (r13) doubles staging
// traffic -> +5us. Keep this exact r11 body (42us measured).
__global__ __launch_bounds__(512, 4) void attn(const bf16_t* __restrict__ Q,
                                               const bf16_t* __restrict__ K,
                                               const bf16_t* __restrict__ VT,
                                               bf16_t* __restrict__ Y) {
  const int L = blockIdx.x;
  const int bh = L & 31;
  const int idx = (L & 255) >> 5;              // 0..7
  const int qi = (L >= 256) ? (15 - 2 * idx) : (2 * idx);
  const int b = bh >> 4, h = bh & 15;
  const int tid = threadIdx.x, l = tid & 63, w = tid >> 6;
  const int qw = w & 3, half = w >> 2;
  const int tid2 = tid & 255;
  const int l31 = l & 31, hi = l >> 5;
  const int hi4 = hi * 4, hi8 = hi * 8;
  const int qbase = qi * 128 + qw * 32;
  const int qown = qbase + l31;
  const int ntile = qi + 1;
  const int t0 = half * ntile, tend = t0 + ntile;
  const int tdiag = qbase >> 6;

  __shared__ __align__(16) char smem[65536];
  char* Kbase = smem + half * 16384;
  char* Vbase = smem + 32768 + half * 16384;

  const bf16_t* Qb = Q + (size_t)bh * 2048 * 64;
  const bf16_t* Kb0 = K + (size_t)bh * 2048 * 64;
  const bf16_t* Vb = VT + (size_t)bh * 64 * 2048;

  bf16x8 qf[4];
  #pragma unroll
  for (int kk = 0; kk < 4; ++kk)
    qf[kk] = *(const bf16x8*)(Qb + (size_t)qown * 64 + kk * 16 + hi8);

  const int srow = tid2 >> 3;          // 0..31
  const int scolb = (tid2 & 7) * 16;   // byte col 0..112
  const int rA = srow, rB = 32 + srow;
  const int swA = scolb ^ ((rA & 7) << 4);
  const int swB = scolb ^ ((rB & 7) << 4);
  const char* KgA = (const char*)Kb0 + (size_t)t0 * 8192 + (size_t)rA * 128 + swA;
  const char* KgB = (const char*)Kb0 + (size_t)t0 * 8192 + (size_t)rB * 128 + swB;
  const char* VgA = (const char*)Vb + (size_t)t0 * 128 + (size_t)rA * 4096 + swA;
  const char* VgB = (const char*)Vb + (size_t)t0 * 128 + (size_t)rB * 4096 + swB;

  f32x16 oa[2];
  #pragma unroll
  for (int dt = 0; dt < 2; ++dt)
    #pragma unroll
    for (int r = 0; r < 16; ++r) oa[dt][r] = 0.f;
  float lacc0 = 0.f, lacc1 = 0.f;

  // prologue: stage tile t0 into buf 0
  gload_lds16(KgA, Kbase + tid2 * 16);
  gload_lds16(KgB, Kbase + 4096 + tid2 * 16);
  gload_lds16(VgA, Vbase + tid2 * 16);
  gload_lds16(VgB, Vbase + 4096 + tid2 * 16);
  KgA += 8192; KgB += 8192; VgA += 128; VgB += 128;
  __syncthreads();

  int cur = 0;
  for (int t = t0; t < tend; ++t) {
    if (t + 1 < tend) {
      char* dK = Kbase + (cur ^ 1) * 8192;
      char* dV = Vbase + (cur ^ 1) * 8192;
      gload_lds16(KgA, dK + tid2 * 16);
      gload_lds16(KgB, dK + 4096 + tid2 * 16);
      gload_lds16(VgA, dV + tid2 * 16);
      gload_lds16(VgB, dV + 4096 + tid2 * 16);
      KgA += 8192; KgB += 8192; VgA += 128; VgB += 128;
    }
    const char* KlH = Kbase + cur * 8192;
    const char* VlH = Vbase + cur * 8192;

    if (t <= tdiag) {                 // wave-uniform: skip fully-masked tiles
      f32x16 s[2];
      #pragma unroll
      for (int sb = 0; sb < 2; ++sb)
        #pragma unroll
        for (int r = 0; r < 16; ++r) s[sb][r] = 0.f;
      __builtin_amdgcn_s_setprio(1);
      #pragma unroll
      for (int sb = 0; sb < 2; ++sb) {
        int row = sb * 32 + l31;
        const char* kr = KlH + row * 128;
        int sw = (row & 7) << 4;
        #pragma unroll
        for (int kk = 0; kk < 4; ++kk) {
          bf16x8 kf = *(const bf16x8*)(kr + ((kk * 32 + hi * 16) ^ sw));
          s[sb] = __builtin_amdgcn_mfma_f32_32x32x16_bf16(kf, qf[kk], s[sb], 0, 0, 0);
        }
      }
      __builtin_amdgcn_s_setprio(0);

      if (t == tdiag) {
        #pragma unroll
        for (int sb = 0; sb < 2; ++sb)
          #pragma unroll
          for (int r = 0; r < 16; ++r) {
            int kv = t * 64 + sb * 32 + (r & 3) + 8 * (r >> 2) + hi4;
            if (kv > qown) s[sb][r] = -__builtin_inff();
          }
      }

      #pragma unroll
      for (int r = 0; r < 16; ++r) {
        float p0 = exp2f(s[0][r]);
        float p1 = exp2f(s[1][r]);
        s[0][r] = p0; lacc0 += p0;
        s[1][r] = p1; lacc1 += p1;
      }

      #pragma unroll
      for (int sb = 0; sb < 2; ++sb) {
        unsigned a0 = pk2(s[sb][0], s[sb][1]),   a1 = pk2(s[sb][2], s[sb][3]);
        unsigned b0 = pk2(s[sb][4], s[sb][5]),   b1 = pk2(s[sb][6], s[sb][7]);
        unsigned c0 = pk2(s[sb][8], s[sb][9]),   c1 = pk2(s[sb][10], s[sb][11]);
        unsigned d0 = pk2(s[sb][12], s[sb][13]), d1 = pk2(s[sb][14], s[sb][15]);
        unsigned r0x, r0y, r1x, r1y, r2x, r2y, r3x, r3y;
        pls(a0, b0, r0x, r0y);
        pls(a1, b1, r1x, r1y);
        pls(c0, d0, r2x, r2y);
        pls(c1, d1, r3x, r3y);
        bf16x8 pf0 = frag4(r0x, r1x, r0y, r1y);
        bf16x8 pf1 = frag4(r2x, r3x, r2y, r3y);
        __builtin_amdgcn_s_setprio(1);
        #pragma unroll
        for (int kk = 0; kk < 2; ++kk) {
          bf16x8 pf = kk ? pf1 : pf0;
          #pragma unroll
          for (int dt = 0; dt < 2; ++dt) {
            int vrow = dt * 32 + l31;
            const char* vr = VlH + vrow * 128;
            bf16x8 vf = *(const bf16x8*)(vr + ((sb * 64 + kk * 32 + hi * 16) ^ ((vrow & 7) << 4)));
            oa[dt] = __builtin_amdgcn_mfma_f32_32x32x16_bf16(vf, pf, oa[dt], 0, 0, 0);
          }
        }
        __builtin_amdgcn_s_setprio(0);
      }
    }

    __syncthreads();   // drains prefetch; protects both LDS buffers
    cur ^= 1;
  }

  // ---- merge halves in LDS (reuse K/V space), normalize, write Y ----
  float lacc = lacc0 + lacc1;
  lacc += __shfl_xor(lacc, 32);
  float* OLDS = (float*)smem;             // [32][256] f32 = 32 KB
  float* LLDS = (float*)(smem + 32768);   // [256] f32 = 1 KB
  if (half == 1) {
    #pragma unroll
    for (int r = 0; r < 32; ++r)
      OLDS[r * 256 + qw * 64 + l] = oa[r >> 4][r & 15];
    LLDS[qw * 64 + l] = lacc;
  }
  __syncthreads();
  if (half == 0) {
    #pragma unroll
    for (int r = 0; r < 32; ++r)
      oa[r >> 4][r & 15] += OLDS[r * 256 + qw * 64 + l];
    float inv = 1.f / (lacc + LLDS[qw * 64 + l]);
    bf16_t* Yb = Y + (size_t)b * 2048 * 1024 + (size_t)qown * 1024 + h * 64;
    #pragma unroll
    for (int dt = 0; dt < 2; ++dt)
      #pragma unroll
      for (int g = 0; g < 4; ++g) {
        bf16x4 v;
        #pragma unroll
        for (int jj = 0; jj < 4; ++jj) v[jj] = (bf16_t)(oa[dt][g * 4 + jj] * inv);
        *(bf16x4*)(Yb + dt * 32 + g * 8 + hi4) = v;
      }
  }
}

// ---------------- launch -----------------------------------------------------
extern "C" void kernel_launch(void* const* d_in, const int* in_sizes, int n_in,
                              void* d_out, int out_size, void* d_ws, size_t ws_size,
                              hipStream_t stream) {
  const float* x = (const float*)d_in[0];
  const float* Wqkv = (const float*)d_in[1];
  const float* Wproj = (const float*)d_in[2];
  float* out = (float*)d_out;
  char* ws = (char*)d_ws;

  bf16_t* xb     = (bf16_t*)(ws + (0u));
  bf16_t* wqkvt  = (bf16_t*)(ws + (8u << 20));
  bf16_t* wprojt = (bf16_t*)(ws + (14u << 20));
  bf16_t* Vtmp   = (bf16_t*)(ws + (16u << 20));
  bf16_t* Q      = (bf16_t*)(ws + (40u << 20));
  bf16_t* Kr     = (bf16_t*)(ws + (48u << 20));
  bf16_t* VT     = (bf16_t*)(ws + (56u << 20));
  bf16_t* Y      = (bf16_t*)(ws + (64u << 20));
  float2* csT    = (float2*)(ws + (72u << 20));

  prep_all<<<dim3(8704), dim3(256), 0, stream>>>(x, Wqkv, Wproj, xb, wqkvt, wprojt, csT);
  gemm_bt<1><<<dim3(24, 64), dim3(256), 0, stream>>>(xb, wqkvt, nullptr, csT, Q, Kr, Vtmp,
                                                     4096, 3072, 1024, 12);
  prep_vt<<<dim3(1024), dim3(256), 0, stream>>>(Vtmp, VT);
  attn<<<dim3(512), dim3(512), 0, stream>>>(Q, Kr, VT, Y);
  gemm_bt<0><<<dim3(8, 64), dim3(256), 0, stream>>>(Y, wprojt, (void*)out, nullptr,
                                                    nullptr, nullptr, nullptr,
                                                    4096, 1024, 1024, 4);
}

// Round 19
// 112.776 us; speedup vs baseline: 1.0293x; 1.0293x over previous
//
#include <hip/hip_runtime.h>
#include <hip/hip_bf16.h>
#include <math.h>

typedef __bf16 bf16_t;
typedef __bf16 bf16x8 __attribute__((ext_vector_type(8)));
typedef __bf16 bf16x4 __attribute__((ext_vector_type(4)));
typedef __bf16 bf16x2 __attribute__((ext_vector_type(2)));
typedef float  f32x4  __attribute__((ext_vector_type(4)));
typedef float  f32x16 __attribute__((ext_vector_type(16)));

// ---------------- async global->LDS (16B per lane, wave-uniform LDS base) ----
__device__ __forceinline__ void gload_lds16(const void* g, void* l) {
  __builtin_amdgcn_global_load_lds((const __attribute__((address_space(1))) void*)g,
                                   (__attribute__((address_space(3))) void*)l,
                                   16, 0, 0);
}

__device__ __forceinline__ unsigned pk2(float a, float b) {
  union { bf16x2 h; unsigned u; } x;
  x.h[0] = (bf16_t)a; x.h[1] = (bf16_t)b;
  return x.u;
}
__device__ __forceinline__ bf16x8 frag4(unsigned w0, unsigned w1, unsigned w2, unsigned w3) {
  union { unsigned u[4]; bf16x8 f; } x;
  x.u[0] = w0; x.u[1] = w1; x.u[2] = w2; x.u[3] = w3;
  return x.f;
}
// permlane32_swap: D.lo=a.lo, D.hi=b.lo ; E.lo=a.hi, E.hi=b.hi  (lane l <-> l^32 mix)
__device__ __forceinline__ void pls(unsigned a, unsigned b, unsigned& x, unsigned& y) {
  auto rr = __builtin_amdgcn_permlane32_swap(a, b, false, false);
  x = ((unsigned*)&rr)[0];
  y = ((unsigned*)&rr)[1];
}

// ---------------- fused prep: x->bf16, W transposes, rope cs table -----------
// grid concat (all independent): [0,4096) convert, [4096,7168) Wqkv^T,
// [7168,8192) Wproj^T, [8192,8704) interleaved (cos,sin) table.
__global__ __launch_bounds__(256) void prep_all(const float* __restrict__ x,
                                                const float* __restrict__ Wqkv,
                                                const float* __restrict__ Wproj,
                                                bf16_t* __restrict__ xb,
                                                bf16_t* __restrict__ wqkvt,
                                                bf16_t* __restrict__ wprojt,
                                                float2* __restrict__ csT) {
  __shared__ float tile[32][33];
  int bx = blockIdx.x;
  if (bx < 4096) {
    int idx = (bx * 256 + threadIdx.x) * 4;
    float4 v = *(const float4*)(x + idx);
    bf16x4 o;
    o[0] = (bf16_t)v.x; o[1] = (bf16_t)v.y; o[2] = (bf16_t)v.z; o[3] = (bf16_t)v.w;
    *(bf16x4*)(xb + idx) = o;
  } else if (bx < 8192) {
    const float* W; bf16_t* Wt; int K, N, n0, k0;
    if (bx < 7168) {
      W = Wqkv; Wt = wqkvt; K = 1024; N = 3072;
      int b = bx - 4096; n0 = (b % 96) * 32; k0 = (b / 96) * 32;
    } else {
      W = Wproj; Wt = wprojt; K = 1024; N = 1024;
      int b = bx - 7168; n0 = (b & 31) * 32; k0 = (b >> 5) * 32;
    }
    int tx = threadIdx.x & 31, ty = threadIdx.x >> 5;
    #pragma unroll
    for (int i = 0; i < 4; ++i) {
      int k = ty + i * 8;
      tile[k][tx] = W[(size_t)(k0 + k) * N + n0 + tx];
    }
    __syncthreads();
    #pragma unroll
    for (int i = 0; i < 4; ++i) {
      int r = ty + i * 8;
      Wt[(size_t)(n0 + r) * K + k0 + tx] = (bf16_t)tile[tx][r];
    }
  } else {
    int b = bx - 8192;
    int t = b * 4 + (threadIdx.x >> 6);
    int d = threadIdx.x & 63;
    float inv = __expf(-logf(10000.f) * (float)(d & 31) * (1.f / 32.f));
    float ang = (float)t * inv;
    float2 cs; cs.x = cosf(ang); cs.y = sinf(ang);
    csT[t * 64 + d] = cs;
  }
}

// ---------------- GEMM: C = A(MxK) * Bt(NxK)^T --------------------------------
// BK=64, single-buffered LDS (r16: dbuf cut occupancy + doubled FETCH -> +18us;
// r18: BM=64 halved compute/barrier -> +6us; 128x128 is the sweet spot).
// T2 swizzle (rule-21). XCD RECTANGLE swizzle: each XCD owns an XW x YH tile
// rectangle so its L2 working set ~5 MB (r17: FETCH 39->22.6 MB).
// MODE 0: plain f32 C (proj). MODE 1: fused QKV epilogue — region-pure blocks
// (bx 0-7 Q, 8-15 K, 16-23 V); RoPE in-register (partner d^32 = acc[m][n^2][r]);
// Q scaled by 0.125*log2(e); V -> compact Vtmp. NOTE r14: fusing V-transpose
// costs VGPR 80->100 -> +18us. Keep Vtmp + separate prep_vt.
template <int MODE>
__global__ __launch_bounds__(256) void gemm_bt(const bf16_t* __restrict__ A,
                                               const bf16_t* __restrict__ Bt,
                                               void* __restrict__ Cout,
                                               const float2* __restrict__ csT,
                                               bf16_t* __restrict__ Qo,
                                               bf16_t* __restrict__ Ko,
                                               bf16_t* __restrict__ Vt,
                                               int M, int N, int K, int XW) {
  const int tid = threadIdx.x;
  const int l = tid & 63, w = tid >> 6;
  const int lr = l & 15, lg = l >> 4;
  const int nwgx = gridDim.x, nwgy = gridDim.y;
  const int orig = blockIdx.y * nwgx + blockIdx.x;
  // XCD rectangle mapping: xcd gets a XW x YH rect; bijective partition.
  const int xcd = orig & 7;
  const int i = orig >> 3;                 // 0 .. nwg/8-1
  const int nrc = nwgx / XW;               // rect columns
  const int YH = (nwgx * nwgy) / (8 * XW); // rect height
  const int bx = (xcd % nrc) * XW + (i % XW);
  const int by = (xcd / nrc) * YH + (i / XW);
  const int wr = w >> 1, wc = w & 1;
  __shared__ __align__(16) bf16_t lA[128 * 64];
  __shared__ __align__(16) bf16_t lB[128 * 64];
  f32x4 acc[4][4];
  const f32x4 zf = {0.f, 0.f, 0.f, 0.f};
  #pragma unroll
  for (int m = 0; m < 4; ++m)
    #pragma unroll
    for (int n = 0; n < 4; ++n) acc[m][n] = zf;

  const int sr8 = l >> 3;                            // 0..7
  const int sc16 = ((l & 7) * 16) ^ (sr8 << 4);      // swizzled src col-byte
  const char* Ab = (const char*)(A + (size_t)(by * 128) * K);
  const char* Bb = (const char*)(Bt + (size_t)(bx * 128) * K);
  const size_t rowb = (size_t)K * 2;                 // row stride bytes

  for (int k0 = 0; k0 < 2 * K; k0 += 128) {
    #pragma unroll
    for (int p = 0; p < 4; ++p) {
      int row = p * 32 + w * 8 + sr8;
      gload_lds16(Ab + (size_t)row * rowb + k0 + sc16, (char*)lA + p * 4096 + w * 1024);
      gload_lds16(Bb + (size_t)row * rowb + k0 + sc16, (char*)lB + p * 4096 + w * 1024);
    }
    __syncthreads();
    #pragma unroll
    for (int kk = 0; kk < 2; ++kk) {
      bf16x8 aF[4], bF[4];
      #pragma unroll
      for (int m = 0; m < 4; ++m) {
        int row = wr * 64 + m * 16 + lr;
        aF[m] = *(const bf16x8*)((const char*)lA + row * 128 +
                                 ((kk * 64 + lg * 16) ^ ((row & 7) << 4)));
      }
      #pragma unroll
      for (int n = 0; n < 4; ++n) {
        int row = wc * 64 + n * 16 + lr;
        bF[n] = *(const bf16x8*)((const char*)lB + row * 128 +
                                 ((kk * 64 + lg * 16) ^ ((row & 7) << 4)));
      }
      #pragma unroll
      for (int m = 0; m < 4; ++m)
        #pragma unroll
        for (int n = 0; n < 4; ++n)
          acc[m][n] = __builtin_amdgcn_mfma_f32_16x16x32_bf16(aF[m], bF[n], acc[m][n], 0, 0, 0);
    }
    __syncthreads();
  }

  const int orow0 = by * 128 + wr * 64;
  if (MODE == 0) {
    const int ocol0 = bx * 128 + wc * 64;
    float* C = (float*)Cout;
    #pragma unroll
    for (int m = 0; m < 4; ++m)
      #pragma unroll
      for (int n = 0; n < 4; ++n)
        #pragma unroll
        for (int r = 0; r < 4; ++r)
          C[(size_t)(orow0 + m * 16 + lg * 4 + r) * N + ocol0 + n * 16 + lr] =
              acc[m][n][r];
  } else {
    const int region = bx >> 3;                 // 0 Q, 1 K, 2 V
    const int h = ((bx & 7) << 1) + wc;         // head within region
    bf16_t* dst = (region == 0) ? Qo : ((region == 1) ? Ko : Vt);
    const float qsc = (region == 0) ? 0.18033688011112042f : 1.0f;
    #pragma unroll
    for (int m = 0; m < 4; ++m)
      #pragma unroll
      for (int r = 0; r < 4; ++r) {
        int grow = orow0 + m * 16 + lg * 4 + r;
        int bb = grow >> 11, t = grow & 2047;
        bf16_t* drow = dst + (((size_t)(bb * 16 + h) * 2048 + t) << 6);
        if (region < 2) {
          #pragma unroll
          for (int n = 0; n < 4; ++n) {
            int d = n * 16 + lr;
            float2 cs = csT[t * 64 + d];
            float v = acc[m][n][r];
            float pv = acc[m][n ^ 2][r];
            float rot = (n < 2) ? -pv : pv;
            drow[d] = (bf16_t)((v * cs.x + rot * cs.y) * qsc);
          }
        } else {
          #pragma unroll
          for (int n = 0; n < 4; ++n)
            drow[n * 16 + lr] = (bf16_t)acc[m][n][r];
        }
      }
  }
}

// ---------------- V transpose: Vtmp (b,h,t,d) -> VT (B,H,Dh,T) ---------------
__global__ __launch_bounds__(256) void prep_vt(const bf16_t* __restrict__ Vtmp,
                                               bf16_t* __restrict__ VT) {
  int bh = blockIdx.x & 31;
  int t0 = (blockIdx.x >> 5) * 64;
  __shared__ __align__(16) bf16_t tile[64][72];
  int r = threadIdx.x >> 2, c4 = threadIdx.x & 3;
  const bf16_t* src = Vtmp + ((size_t)bh * 2048 + t0 + r) * 64 + c4 * 16;
  *(bf16x8*)&tile[r][c4 * 16] = *(const bf16x8*)src;
  *(bf16x8*)&tile[r][c4 * 16 + 8] = *(const bf16x8*)(src + 8);
  __syncthreads();
  bf16x8 v0, v1;
  #pragma unroll
  for (int i = 0; i < 8; ++i) v0[i] = tile[c4 * 16 + i][r];
  #pragma unroll
  for (int i = 0; i < 8; ++i) v1[i] = tile[c4 * 16 + 8 + i][r];
  bf16_t* dst = VT + ((size_t)bh * 64 + r) * 2048 + t0 + c4 * 16;
  *(bf16x8*)dst = v0;
  *(bf16x8*)(dst + 8) = v1;
}

// ---------------- causal flash attention --------------------------------------
// 512 blocks x 512 threads (8 waves = 4 q-waves x 2 kv-halves). Each (bh, qi)
// exactly once; slot-balanced pairing (block c and c+256 share a CU slot).
// Double-buffered K/V per half; LDS 64 KB, 2 blocks/CU. bh = L&31 keeps
// XCD/L2 grouping. No max tracking. Swapped-QK 32x32 MFMA; permlane P-pack.
// NOTE: oacc[2][2] 4-chain variant overflows unified VGPR/AGPR -> spills
// (r10: FETCH 12->58 MB, 2x time). q-half block split (r13) doubles staging
// traffic -> +5us. Keep this exact r11 body (42us measured).
__global__ __launch_bounds__(512, 4) void attn(const bf16_t* __restrict__ Q,
                                               const bf16_t* __restrict__ K,
                                               const bf16_t* __restrict__ VT,
                                               bf16_t* __restrict__ Y) {
  const int L = blockIdx.x;
  const int bh = L & 31;
  const int idx = (L & 255) >> 5;              // 0..7
  const int qi = (L >= 256) ? (15 - 2 * idx) : (2 * idx);
  const int b = bh >> 4, h = bh & 15;
  const int tid = threadIdx.x, l = tid & 63, w = tid >> 6;
  const int qw = w & 3, half = w >> 2;
  const int tid2 = tid & 255;
  const int l31 = l & 31, hi = l >> 5;
  const int hi4 = hi * 4, hi8 = hi * 8;
  const int qbase = qi * 128 + qw * 32;
  const int qown = qbase + l31;
  const int ntile = qi + 1;
  const int t0 = half * ntile, tend = t0 + ntile;
  const int tdiag = qbase >> 6;

  __shared__ __align__(16) char smem[65536];
  char* Kbase = smem + half * 16384;
  char* Vbase = smem + 32768 + half * 16384;

  const bf16_t* Qb = Q + (size_t)bh * 2048 * 64;
  const bf16_t* Kb0 = K + (size_t)bh * 2048 * 64;
  const bf16_t* Vb = VT + (size_t)bh * 64 * 2048;

  bf16x8 qf[4];
  #pragma unroll
  for (int kk = 0; kk < 4; ++kk)
    qf[kk] = *(const bf16x8*)(Qb + (size_t)qown * 64 + kk * 16 + hi8);

  const int srow = tid2 >> 3;          // 0..31
  const int scolb = (tid2 & 7) * 16;   // byte col 0..112
  const int rA = srow, rB = 32 + srow;
  const int swA = scolb ^ ((rA & 7) << 4);
  const int swB = scolb ^ ((rB & 7) << 4);
  const char* KgA = (const char*)Kb0 + (size_t)t0 * 8192 + (size_t)rA * 128 + swA;
  const char* KgB = (const char*)Kb0 + (size_t)t0 * 8192 + (size_t)rB * 128 + swB;
  const char* VgA = (const char*)Vb + (size_t)t0 * 128 + (size_t)rA * 4096 + swA;
  const char* VgB = (const char*)Vb + (size_t)t0 * 128 + (size_t)rB * 4096 + swB;

  f32x16 oa[2];
  #pragma unroll
  for (int dt = 0; dt < 2; ++dt)
    #pragma unroll
    for (int r = 0; r < 16; ++r) oa[dt][r] = 0.f;
  float lacc0 = 0.f, lacc1 = 0.f;

  // prologue: stage tile t0 into buf 0
  gload_lds16(KgA, Kbase + tid2 * 16);
  gload_lds16(KgB, Kbase + 4096 + tid2 * 16);
  gload_lds16(VgA, Vbase + tid2 * 16);
  gload_lds16(VgB, Vbase + 4096 + tid2 * 16);
  KgA += 8192; KgB += 8192; VgA += 128; VgB += 128;
  __syncthreads();

  int cur = 0;
  for (int t = t0; t < tend; ++t) {
    if (t + 1 < tend) {
      char* dK = Kbase + (cur ^ 1) * 8192;
      char* dV = Vbase + (cur ^ 1) * 8192;
      gload_lds16(KgA, dK + tid2 * 16);
      gload_lds16(KgB, dK + 4096 + tid2 * 16);
      gload_lds16(VgA, dV + tid2 * 16);
      gload_lds16(VgB, dV + 4096 + tid2 * 16);
      KgA += 8192; KgB += 8192; VgA += 128; VgB += 128;
    }
    const char* KlH = Kbase + cur * 8192;
    const char* VlH = Vbase + cur * 8192;

    if (t <= tdiag) {                 // wave-uniform: skip fully-masked tiles
      f32x16 s[2];
      #pragma unroll
      for (int sb = 0; sb < 2; ++sb)
        #pragma unroll
        for (int r = 0; r < 16; ++r) s[sb][r] = 0.f;
      __builtin_amdgcn_s_setprio(1);
      #pragma unroll
      for (int sb = 0; sb < 2; ++sb) {
        int row = sb * 32 + l31;
        const char* kr = KlH + row * 128;
        int sw = (row & 7) << 4;
        #pragma unroll
        for (int kk = 0; kk < 4; ++kk) {
          bf16x8 kf = *(const bf16x8*)(kr + ((kk * 32 + hi * 16) ^ sw));
          s[sb] = __builtin_amdgcn_mfma_f32_32x32x16_bf16(kf, qf[kk], s[sb], 0, 0, 0);
        }
      }
      __builtin_amdgcn_s_setprio(0);

      if (t == tdiag) {
        #pragma unroll
        for (int sb = 0; sb < 2; ++sb)
          #pragma unroll
          for (int r = 0; r < 16; ++r) {
            int kv = t * 64 + sb * 32 + (r & 3) + 8 * (r >> 2) + hi4;
            if (kv > qown) s[sb][r] = -__builtin_inff();
          }
      }

      #pragma unroll
      for (int r = 0; r < 16; ++r) {
        float p0 = exp2f(s[0][r]);
        float p1 = exp2f(s[1][r]);
        s[0][r] = p0; lacc0 += p0;
        s[1][r] = p1; lacc1 += p1;
      }

      #pragma unroll
      for (int sb = 0; sb < 2; ++sb) {
        unsigned a0 = pk2(s[sb][0], s[sb][1]),   a1 = pk2(s[sb][2], s[sb][3]);
        unsigned b0 = pk2(s[sb][4], s[sb][5]),   b1 = pk2(s[sb][6], s[sb][7]);
        unsigned c0 = pk2(s[sb][8], s[sb][9]),   c1 = pk2(s[sb][10], s[sb][11]);
        unsigned d0 = pk2(s[sb][12], s[sb][13]), d1 = pk2(s[sb][14], s[sb][15]);
        unsigned r0x, r0y, r1x, r1y, r2x, r2y, r3x, r3y;
        pls(a0, b0, r0x, r0y);
        pls(a1, b1, r1x, r1y);
        pls(c0, d0, r2x, r2y);
        pls(c1, d1, r3x, r3y);
        bf16x8 pf0 = frag4(r0x, r1x, r0y, r1y);
        bf16x8 pf1 = frag4(r2x, r3x, r2y, r3y);
        __builtin_amdgcn_s_setprio(1);
        #pragma unroll
        for (int kk = 0; kk < 2; ++kk) {
          bf16x8 pf = kk ? pf1 : pf0;
          #pragma unroll
          for (int dt = 0; dt < 2; ++dt) {
            int vrow = dt * 32 + l31;
            const char* vr = VlH + vrow * 128;
            bf16x8 vf = *(const bf16x8*)(vr + ((sb * 64 + kk * 32 + hi * 16) ^ ((vrow & 7) << 4)));
            oa[dt] = __builtin_amdgcn_mfma_f32_32x32x16_bf16(vf, pf, oa[dt], 0, 0, 0);
          }
        }
        __builtin_amdgcn_s_setprio(0);
      }
    }

    __syncthreads();   // drains prefetch; protects both LDS buffers
    cur ^= 1;
  }

  // ---- merge halves in LDS (reuse K/V space), normalize, write Y ----
  float lacc = lacc0 + lacc1;
  lacc += __shfl_xor(lacc, 32);
  float* OLDS = (float*)smem;             // [32][256] f32 = 32 KB
  float* LLDS = (float*)(smem + 32768);   // [256] f32 = 1 KB
  if (half == 1) {
    #pragma unroll
    for (int r = 0; r < 32; ++r)
      OLDS[r * 256 + qw * 64 + l] = oa[r >> 4][r & 15];
    LLDS[qw * 64 + l] = lacc;
  }
  __syncthreads();
  if (half == 0) {
    #pragma unroll
    for (int r = 0; r < 32; ++r)
      oa[r >> 4][r & 15] += OLDS[r * 256 + qw * 64 + l];
    float inv = 1.f / (lacc + LLDS[qw * 64 + l]);
    bf16_t* Yb = Y + (size_t)b * 2048 * 1024 + (size_t)qown * 1024 + h * 64;
    #pragma unroll
    for (int dt = 0; dt < 2; ++dt)
      #pragma unroll
      for (int g = 0; g < 4; ++g) {
        bf16x4 v;
        #pragma unroll
        for (int jj = 0; jj < 4; ++jj) v[jj] = (bf16_t)(oa[dt][g * 4 + jj] * inv);
        *(bf16x4*)(Yb + dt * 32 + g * 8 + hi4) = v;
      }
  }
}

// ---------------- launch -----------------------------------------------------
extern "C" void kernel_launch(void* const* d_in, const int* in_sizes, int n_in,
                              void* d_out, int out_size, void* d_ws, size_t ws_size,
                              hipStream_t stream) {
  const float* x = (const float*)d_in[0];
  const float* Wqkv = (const float*)d_in[1];
  const float* Wproj = (const float*)d_in[2];
  float* out = (float*)d_out;
  char* ws = (char*)d_ws;

  bf16_t* xb     = (bf16_t*)(ws + (0u));
  bf16_t* wqkvt  = (bf16_t*)(ws + (8u << 20));
  bf16_t* wprojt = (bf16_t*)(ws + (14u << 20));
  bf16_t* Vtmp   = (bf16_t*)(ws + (16u << 20));
  bf16_t* Q      = (bf16_t*)(ws + (40u << 20));
  bf16_t* Kr     = (bf16_t*)(ws + (48u << 20));
  bf16_t* VT     = (bf16_t*)(ws + (56u << 20));
  bf16_t* Y      = (bf16_t*)(ws + (64u << 20));
  float2* csT    = (float2*)(ws + (72u << 20));

  prep_all<<<dim3(8704), dim3(256), 0, stream>>>(x, Wqkv, Wproj, xb, wqkvt, wprojt, csT);
  gemm_bt<1><<<dim3(24, 32), dim3(256), 0, stream>>>(xb, wqkvt, nullptr, csT, Q, Kr, Vtmp,
                                                     4096, 3072, 1024, 12);
  prep_vt<<<dim3(1024), dim3(256), 0, stream>>>(Vtmp, VT);
  attn<<<dim3(512), dim3(512), 0, stream>>>(Q, Kr, VT, Y);
  gemm_bt<0><<<dim3(8, 32), dim3(256), 0, stream>>>(Y, wprojt, (void*)out, nullptr,
                                                    nullptr, nullptr, nullptr,
                                                    4096, 1024, 1024, 4);
}

// Round 20
// 108.252 us; speedup vs baseline: 1.0723x; 1.0418x over previous
//
#include <hip/hip_runtime.h>
#include <hip/hip_bf16.h>
#include <math.h>

typedef __bf16 bf16_t;
typedef __bf16 bf16x8 __attribute__((ext_vector_type(8)));
typedef __bf16 bf16x4 __attribute__((ext_vector_type(4)));
typedef __bf16 bf16x2 __attribute__((ext_vector_type(2)));
typedef float  f32x4  __attribute__((ext_vector_type(4)));
typedef float  f32x16 __attribute__((ext_vector_type(16)));

// ---------------- async global->LDS (16B per lane, wave-uniform LDS base) ----
__device__ __forceinline__ void gload_lds16(const void* g, void* l) {
  __builtin_amdgcn_global_load_lds((const __attribute__((address_space(1))) void*)g,
                                   (__attribute__((address_space(3))) void*)l,
                                   16, 0, 0);
}

__device__ __forceinline__ unsigned pk2(float a, float b) {
  union { bf16x2 h; unsigned u; } x;
  x.h[0] = (bf16_t)a; x.h[1] = (bf16_t)b;
  return x.u;
}
__device__ __forceinline__ bf16x8 frag4(unsigned w0, unsigned w1, unsigned w2, unsigned w3) {
  union { unsigned u[4]; bf16x8 f; } x;
  x.u[0] = w0; x.u[1] = w1; x.u[2] = w2; x.u[3] = w3;
  return x.f;
}
// permlane32_swap: D.lo=a.lo, D.hi=b.lo ; E.lo=a.hi, E.hi=b.hi  (lane l <-> l^32 mix)
__device__ __forceinline__ void pls(unsigned a, unsigned b, unsigned& x, unsigned& y) {
  auto rr = __builtin_amdgcn_permlane32_swap(a, b, false, false);
  x = ((unsigned*)&rr)[0];
  y = ((unsigned*)&rr)[1];
}

// ---------------- fused prep: x->bf16, W transposes, rope cs table -----------
// grid concat (all independent): [0,4096) convert, [4096,7168) Wqkv^T,
// [7168,8192) Wproj^T, [8192,8704) interleaved (cos,sin) table.
__global__ __launch_bounds__(256) void prep_all(const float* __restrict__ x,
                                                const float* __restrict__ Wqkv,
                                                const float* __restrict__ Wproj,
                                                bf16_t* __restrict__ xb,
                                                bf16_t* __restrict__ wqkvt,
                                                bf16_t* __restrict__ wprojt,
                                                float2* __restrict__ csT) {
  __shared__ float tile[32][33];
  int bx = blockIdx.x;
  if (bx < 4096) {
    int idx = (bx * 256 + threadIdx.x) * 4;
    float4 v = *(const float4*)(x + idx);
    bf16x4 o;
    o[0] = (bf16_t)v.x; o[1] = (bf16_t)v.y; o[2] = (bf16_t)v.z; o[3] = (bf16_t)v.w;
    *(bf16x4*)(xb + idx) = o;
  } else if (bx < 8192) {
    const float* W; bf16_t* Wt; int K, N, n0, k0;
    if (bx < 7168) {
      W = Wqkv; Wt = wqkvt; K = 1024; N = 3072;
      int b = bx - 4096; n0 = (b % 96) * 32; k0 = (b / 96) * 32;
    } else {
      W = Wproj; Wt = wprojt; K = 1024; N = 1024;
      int b = bx - 7168; n0 = (b & 31) * 32; k0 = (b >> 5) * 32;
    }
    int tx = threadIdx.x & 31, ty = threadIdx.x >> 5;
    #pragma unroll
    for (int i = 0; i < 4; ++i) {
      int k = ty + i * 8;
      tile[k][tx] = W[(size_t)(k0 + k) * N + n0 + tx];
    }
    __syncthreads();
    #pragma unroll
    for (int i = 0; i < 4; ++i) {
      int r = ty + i * 8;
      Wt[(size_t)(n0 + r) * K + k0 + tx] = (bf16_t)tile[tx][r];
    }
  } else {
    int b = bx - 8192;
    int t = b * 4 + (threadIdx.x >> 6);
    int d = threadIdx.x & 63;
    float inv = __expf(-logf(10000.f) * (float)(d & 31) * (1.f / 32.f));
    float ang = (float)t * inv;
    float2 cs; cs.x = cosf(ang); cs.y = sinf(ang);
    csT[t * 64 + d] = cs;
  }
}

// ---------------- GEMM: C = A(MxK) * Bt(NxK)^T --------------------------------
// BM x 128 tile, BK=64, single-buffered LDS. T2 swizzle (rule-21). XCD
// RECTANGLE swizzle (per-XCD L2 working set ~5 MB; r17: FETCH 39->22.6 MB).
// BM=128 for QKV (r18: BM=64 halves compute/barrier -> +6us there);
// BM=64 for PROJ (grid 256->512 blocks = 2 blocks/CU; 1 block/CU has zero
// cross-block latency cover — r18 decomposition showed proj gained ~2us).
// MODE 0: plain f32 C (proj). MODE 1: fused QKV epilogue — region-pure blocks
// (bx 0-7 Q, 8-15 K, 16-23 V); RoPE in-register (partner d^32 = acc[m][n^2][r]);
// Q scaled by 0.125*log2(e); V -> compact Vtmp. NOTE r14: fusing V-transpose
// costs VGPR 80->100 -> +18us. Keep Vtmp + separate prep_vt.
template <int MODE, int BM>
__global__ __launch_bounds__(256) void gemm_bt(const bf16_t* __restrict__ A,
                                               const bf16_t* __restrict__ Bt,
                                               void* __restrict__ Cout,
                                               const float2* __restrict__ csT,
                                               bf16_t* __restrict__ Qo,
                                               bf16_t* __restrict__ Ko,
                                               bf16_t* __restrict__ Vt,
                                               int M, int N, int K, int XW) {
  constexpr int MACC = BM / 32;              // acc rows per wave
  const int tid = threadIdx.x;
  const int l = tid & 63, w = tid >> 6;
  const int lr = l & 15, lg = l >> 4;
  const int nwgx = gridDim.x, nwgy = gridDim.y;
  const int orig = blockIdx.y * nwgx + blockIdx.x;
  // XCD rectangle mapping: xcd gets a XW x YH rect; bijective partition.
  const int xcd = orig & 7;
  const int i = orig >> 3;                 // 0 .. nwg/8-1
  const int nrc = nwgx / XW;               // rect columns
  const int YH = (nwgx * nwgy) / (8 * XW); // rect height
  const int bx = (xcd % nrc) * XW + (i % XW);
  const int by = (xcd / nrc) * YH + (i / XW);
  const int wr = w >> 1, wc = w & 1;
  __shared__ __align__(16) bf16_t lA[BM * 64];
  __shared__ __align__(16) bf16_t lB[128 * 64];
  f32x4 acc[MACC][4];
  const f32x4 zf = {0.f, 0.f, 0.f, 0.f};
  #pragma unroll
  for (int m = 0; m < MACC; ++m)
    #pragma unroll
    for (int n = 0; n < 4; ++n) acc[m][n] = zf;

  const int sr8 = l >> 3;                            // 0..7
  const int sc16 = ((l & 7) * 16) ^ (sr8 << 4);      // swizzled src col-byte
  const char* Ab = (const char*)(A + (size_t)(by * BM) * K);
  const char* Bb = (const char*)(Bt + (size_t)(bx * 128) * K);
  const size_t rowb = (size_t)K * 2;                 // row stride bytes

  for (int k0 = 0; k0 < 2 * K; k0 += 128) {
    #pragma unroll
    for (int p = 0; p < MACC; ++p) {
      int row = p * 32 + w * 8 + sr8;
      gload_lds16(Ab + (size_t)row * rowb + k0 + sc16, (char*)lA + p * 4096 + w * 1024);
    }
    #pragma unroll
    for (int p = 0; p < 4; ++p) {
      int row = p * 32 + w * 8 + sr8;
      gload_lds16(Bb + (size_t)row * rowb + k0 + sc16, (char*)lB + p * 4096 + w * 1024);
    }
    __syncthreads();
    #pragma unroll
    for (int kk = 0; kk < 2; ++kk) {
      bf16x8 aF[MACC], bF[4];
      #pragma unroll
      for (int m = 0; m < MACC; ++m) {
        int row = wr * (BM / 2) + m * 16 + lr;
        aF[m] = *(const bf16x8*)((const char*)lA + row * 128 +
                                 ((kk * 64 + lg * 16) ^ ((row & 7) << 4)));
      }
      #pragma unroll
      for (int n = 0; n < 4; ++n) {
        int row = wc * 64 + n * 16 + lr;
        bF[n] = *(const bf16x8*)((const char*)lB + row * 128 +
                                 ((kk * 64 + lg * 16) ^ ((row & 7) << 4)));
      }
      #pragma unroll
      for (int m = 0; m < MACC; ++m)
        #pragma unroll
        for (int n = 0; n < 4; ++n)
          acc[m][n] = __builtin_amdgcn_mfma_f32_16x16x32_bf16(aF[m], bF[n], acc[m][n], 0, 0, 0);
    }
    __syncthreads();
  }

  const int orow0 = by * BM + wr * (BM / 2);
  if (MODE == 0) {
    const int ocol0 = bx * 128 + wc * 64;
    float* C = (float*)Cout;
    #pragma unroll
    for (int m = 0; m < MACC; ++m)
      #pragma unroll
      for (int n = 0; n < 4; ++n)
        #pragma unroll
        for (int r = 0; r < 4; ++r)
          C[(size_t)(orow0 + m * 16 + lg * 4 + r) * N + ocol0 + n * 16 + lr] =
              acc[m][n][r];
  } else {
    const int region = bx >> 3;                 // 0 Q, 1 K, 2 V
    const int h = ((bx & 7) << 1) + wc;         // head within region
    bf16_t* dst = (region == 0) ? Qo : ((region == 1) ? Ko : Vt);
    const float qsc = (region == 0) ? 0.18033688011112042f : 1.0f;
    #pragma unroll
    for (int m = 0; m < MACC; ++m)
      #pragma unroll
      for (int r = 0; r < 4; ++r) {
        int grow = orow0 + m * 16 + lg * 4 + r;
        int bb = grow >> 11, t = grow & 2047;
        bf16_t* drow = dst + (((size_t)(bb * 16 + h) * 2048 + t) << 6);
        if (region < 2) {
          #pragma unroll
          for (int n = 0; n < 4; ++n) {
            int d = n * 16 + lr;
            float2 cs = csT[t * 64 + d];
            float v = acc[m][n][r];
            float pv = acc[m][n ^ 2][r];
            float rot = (n < 2) ? -pv : pv;
            drow[d] = (bf16_t)((v * cs.x + rot * cs.y) * qsc);
          }
        } else {
          #pragma unroll
          for (int n = 0; n < 4; ++n)
            drow[n * 16 + lr] = (bf16_t)acc[m][n][r];
        }
      }
  }
}

// ---------------- V transpose: Vtmp (b,h,t,d) -> VT (B,H,Dh,T) ---------------
__global__ __launch_bounds__(256) void prep_vt(const bf16_t* __restrict__ Vtmp,
                                               bf16_t* __restrict__ VT) {
  int bh = blockIdx.x & 31;
  int t0 = (blockIdx.x >> 5) * 64;
  __shared__ __align__(16) bf16_t tile[64][72];
  int r = threadIdx.x >> 2, c4 = threadIdx.x & 3;
  const bf16_t* src = Vtmp + ((size_t)bh * 2048 + t0 + r) * 64 + c4 * 16;
  *(bf16x8*)&tile[r][c4 * 16] = *(const bf16x8*)src;
  *(bf16x8*)&tile[r][c4 * 16 + 8] = *(const bf16x8*)(src + 8);
  __syncthreads();
  bf16x8 v0, v1;
  #pragma unroll
  for (int i = 0; i < 8; ++i) v0[i] = tile[c4 * 16 + i][r];
  #pragma unroll
  for (int i = 0; i < 8; ++i) v1[i] = tile[c4 * 16 + 8 + i][r];
  bf16_t* dst = VT + ((size_t)bh * 64 + r) * 2048 + t0 + c4 * 16;
  *(bf16x8*)dst = v0;
  *(bf16x8*)(dst + 8) = v1;
}

// ---------------- causal flash attention --------------------------------------
// 512 blocks x 512 threads (8 waves = 4 q-waves x 2 kv-halves). Each (bh, qi)
// exactly once; slot-balanced pairing (block c and c+256 share a CU slot).
// Double-buffered K/V per half; LDS 64 KB, 2 blocks/CU. bh = L&31 keeps
// XCD/L2 grouping. No max tracking. Swapped-QK 32x32 MFMA; permlane P-pack.
// NOTE: oacc[2][2] 4-chain variant overflows unified VGPR/AGPR -> spills
// (r10: FETCH 12->58 MB, 2x time). q-half block split (r13) doubles staging
// traffic -> +5us. Keep this exact r11 body (42us measured).
__global__ __launch_bounds__(512, 4) void attn(const bf16_t* __restrict__ Q,
                                               const bf16_t* __restrict__ K,
                                               const bf16_t* __restrict__ VT,
                                               bf16_t* __restrict__ Y) {
  const int L = blockIdx.x;
  const int bh = L & 31;
  const int idx = (L & 255) >> 5;              // 0..7
  const int qi = (L >= 256) ? (15 - 2 * idx) : (2 * idx);
  const int b = bh >> 4, h = bh & 15;
  const int tid = threadIdx.x, l = tid & 63, w = tid >> 6;
  const int qw = w & 3, half = w >> 2;
  const int tid2 = tid & 255;
  const int l31 = l & 31, hi = l >> 5;
  const int hi4 = hi * 4, hi8 = hi * 8;
  const int qbase = qi * 128 + qw * 32;
  const int qown = qbase + l31;
  const int ntile = qi + 1;
  const int t0 = half * ntile, tend = t0 + ntile;
  const int tdiag = qbase >> 6;

  __shared__ __align__(16) char smem[65536];
  char* Kbase = smem + half * 16384;
  char* Vbase = smem + 32768 + half * 16384;

  const bf16_t* Qb = Q + (size_t)bh * 2048 * 64;
  const bf16_t* Kb0 = K + (size_t)bh * 2048 * 64;
  const bf16_t* Vb = VT + (size_t)bh * 64 * 2048;

  bf16x8 qf[4];
  #pragma unroll
  for (int kk = 0; kk < 4; ++kk)
    qf[kk] = *(const bf16x8*)(Qb + (size_t)qown * 64 + kk * 16 + hi8);

  const int srow = tid2 >> 3;          // 0..31
  const int scolb = (tid2 & 7) * 16;   // byte col 0..112
  const int rA = srow, rB = 32 + srow;
  const int swA = scolb ^ ((rA & 7) << 4);
  const int swB = scolb ^ ((rB & 7) << 4);
  const char* KgA = (const char*)Kb0 + (size_t)t0 * 8192 + (size_t)rA * 128 + swA;
  const char* KgB = (const char*)Kb0 + (size_t)t0 * 8192 + (size_t)rB * 128 + swB;
  const char* VgA = (const char*)Vb + (size_t)t0 * 128 + (size_t)rA * 4096 + swA;
  const char* VgB = (const char*)Vb + (size_t)t0 * 128 + (size_t)rB * 4096 + swB;

  f32x16 oa[2];
  #pragma unroll
  for (int dt = 0; dt < 2; ++dt)
    #pragma unroll
    for (int r = 0; r < 16; ++r) oa[dt][r] = 0.f;
  float lacc0 = 0.f, lacc1 = 0.f;

  // prologue: stage tile t0 into buf 0
  gload_lds16(KgA, Kbase + tid2 * 16);
  gload_lds16(KgB, Kbase + 4096 + tid2 * 16);
  gload_lds16(VgA, Vbase + tid2 * 16);
  gload_lds16(VgB, Vbase + 4096 + tid2 * 16);
  KgA += 8192; KgB += 8192; VgA += 128; VgB += 128;
  __syncthreads();

  int cur = 0;
  for (int t = t0; t < tend; ++t) {
    if (t + 1 < tend) {
      char* dK = Kbase + (cur ^ 1) * 8192;
      char* dV = Vbase + (cur ^ 1) * 8192;
      gload_lds16(KgA, dK + tid2 * 16);
      gload_lds16(KgB, dK + 4096 + tid2 * 16);
      gload_lds16(VgA, dV + tid2 * 16);
      gload_lds16(VgB, dV + 4096 + tid2 * 16);
      KgA += 8192; KgB += 8192; VgA += 128; VgB += 128;
    }
    const char* KlH = Kbase + cur * 8192;
    const char* VlH = Vbase + cur * 8192;

    if (t <= tdiag) {                 // wave-uniform: skip fully-masked tiles
      f32x16 s[2];
      #pragma unroll
      for (int sb = 0; sb < 2; ++sb)
        #pragma unroll
        for (int r = 0; r < 16; ++r) s[sb][r] = 0.f;
      __builtin_amdgcn_s_setprio(1);
      #pragma unroll
      for (int sb = 0; sb < 2; ++sb) {
        int row = sb * 32 + l31;
        const char* kr = KlH + row * 128;
        int sw = (row & 7) << 4;
        #pragma unroll
        for (int kk = 0; kk < 4; ++kk) {
          bf16x8 kf = *(const bf16x8*)(kr + ((kk * 32 + hi * 16) ^ sw));
          s[sb] = __builtin_amdgcn_mfma_f32_32x32x16_bf16(kf, qf[kk], s[sb], 0, 0, 0);
        }
      }
      __builtin_amdgcn_s_setprio(0);

      if (t == tdiag) {
        #pragma unroll
        for (int sb = 0; sb < 2; ++sb)
          #pragma unroll
          for (int r = 0; r < 16; ++r) {
            int kv = t * 64 + sb * 32 + (r & 3) + 8 * (r >> 2) + hi4;
            if (kv > qown) s[sb][r] = -__builtin_inff();
          }
      }

      #pragma unroll
      for (int r = 0; r < 16; ++r) {
        float p0 = exp2f(s[0][r]);
        float p1 = exp2f(s[1][r]);
        s[0][r] = p0; lacc0 += p0;
        s[1][r] = p1; lacc1 += p1;
      }

      #pragma unroll
      for (int sb = 0; sb < 2; ++sb) {
        unsigned a0 = pk2(s[sb][0], s[sb][1]),   a1 = pk2(s[sb][2], s[sb][3]);
        unsigned b0 = pk2(s[sb][4], s[sb][5]),   b1 = pk2(s[sb][6], s[sb][7]);
        unsigned c0 = pk2(s[sb][8], s[sb][9]),   c1 = pk2(s[sb][10], s[sb][11]);
        unsigned d0 = pk2(s[sb][12], s[sb][13]), d1 = pk2(s[sb][14], s[sb][15]);
        unsigned r0x, r0y, r1x, r1y, r2x, r2y, r3x, r3y;
        pls(a0, b0, r0x, r0y);
        pls(a1, b1, r1x, r1y);
        pls(c0, d0, r2x, r2y);
        pls(c1, d1, r3x, r3y);
        bf16x8 pf0 = frag4(r0x, r1x, r0y, r1y);
        bf16x8 pf1 = frag4(r2x, r3x, r2y, r3y);
        __builtin_amdgcn_s_setprio(1);
        #pragma unroll
        for (int kk = 0; kk < 2; ++kk) {
          bf16x8 pf = kk ? pf1 : pf0;
          #pragma unroll
          for (int dt = 0; dt < 2; ++dt) {
            int vrow = dt * 32 + l31;
            const char* vr = VlH + vrow * 128;
            bf16x8 vf = *(const bf16x8*)(vr + ((sb * 64 + kk * 32 + hi * 16) ^ ((vrow & 7) << 4)));
            oa[dt] = __builtin_amdgcn_mfma_f32_32x32x16_bf16(vf, pf, oa[dt], 0, 0, 0);
          }
        }
        __builtin_amdgcn_s_setprio(0);
      }
    }

    __syncthreads();   // drains prefetch; protects both LDS buffers
    cur ^= 1;
  }

  // ---- merge halves in LDS (reuse K/V space), normalize, write Y ----
  float lacc = lacc0 + lacc1;
  lacc += __shfl_xor(lacc, 32);
  float* OLDS = (float*)smem;             // [32][256] f32 = 32 KB
  float* LLDS = (float*)(smem + 32768);   // [256] f32 = 1 KB
  if (half == 1) {
    #pragma unroll
    for (int r = 0; r < 32; ++r)
      OLDS[r * 256 + qw * 64 + l] = oa[r >> 4][r & 15];
    LLDS[qw * 64 + l] = lacc;
  }
  __syncthreads();
  if (half == 0) {
    #pragma unroll
    for (int r = 0; r < 32; ++r)
      oa[r >> 4][r & 15] += OLDS[r * 256 + qw * 64 + l];
    float inv = 1.f / (lacc + LLDS[qw * 64 + l]);
    bf16_t* Yb = Y + (size_t)b * 2048 * 1024 + (size_t)qown * 1024 + h * 64;
    #pragma unroll
    for (int dt = 0; dt < 2; ++dt)
      #pragma unroll
      for (int g = 0; g < 4; ++g) {
        bf16x4 v;
        #pragma unroll
        for (int jj = 0; jj < 4; ++jj) v[jj] = (bf16_t)(oa[dt][g * 4 + jj] * inv);
        *(bf16x4*)(Yb + dt * 32 + g * 8 + hi4) = v;
      }
  }
}

// ---------------- launch -----------------------------------------------------
extern "C" void kernel_launch(void* const* d_in, const int* in_sizes, int n_in,
                              void* d_out, int out_size, void* d_ws, size_t ws_size,
                              hipStream_t stream) {
  const float* x = (const float*)d_in[0];
  const float* Wqkv = (const float*)d_in[1];
  const float* Wproj = (const float*)d_in[2];
  float* out = (float*)d_out;
  char* ws = (char*)d_ws;

  bf16_t* xb     = (bf16_t*)(ws + (0u));
  bf16_t* wqkvt  = (bf16_t*)(ws + (8u << 20));
  bf16_t* wprojt = (bf16_t*)(ws + (14u << 20));
  bf16_t* Vtmp   = (bf16_t*)(ws + (16u << 20));
  bf16_t* Q      = (bf16_t*)(ws + (40u << 20));
  bf16_t* Kr     = (bf16_t*)(ws + (48u << 20));
  bf16_t* VT     = (bf16_t*)(ws + (56u << 20));
  bf16_t* Y      = (bf16_t*)(ws + (64u << 20));
  float2* csT    = (float2*)(ws + (72u << 20));

  prep_all<<<dim3(8704), dim3(256), 0, stream>>>(x, Wqkv, Wproj, xb, wqkvt, wprojt, csT);
  gemm_bt<1, 128><<<dim3(24, 32), dim3(256), 0, stream>>>(xb, wqkvt, nullptr, csT, Q, Kr, Vtmp,
                                                          4096, 3072, 1024, 12);
  prep_vt<<<dim3(1024), dim3(256), 0, stream>>>(Vtmp, VT);
  attn<<<dim3(512), dim3(512), 0, stream>>>(Q, Kr, VT, Y);
  gemm_bt<0, 64><<<dim3(8, 64), dim3(256), 0, stream>>>(Y, wprojt, (void*)out, nullptr,
                                                        nullptr, nullptr, nullptr,
                                                        4096, 1024, 1024, 4);
}